// Round 9
// baseline (332.097 us; speedup 1.0000x reference)
//
#include <hip/hip_runtime.h>
#include <hip/hip_bf16.h>

// Problem constants
#define NEGV  (-1000000.0f)
#define OUT_ELEMS   19267584     // 64*64*49*96 (att follows in d_out)

// ws layout (bytes):
//  [0)      packed bf16 B-fragments: Wb1 27648 ushorts, Wb2 9216 ushorts
//  [73728)  vbuf bf16 [4096][49][96] = 38,535,168 B
#define WB2_USH     27648
#define VBUF_OFF_B  73728

// K_A LDS layout (ushort offsets)
#define XT_OFF     0
#define KQ_OFF     6656
#define KQ_Q_OFF   (KQ_OFF + 15680)
#define SMEM_A_USH (6656 + 31360 + 640)

typedef __bf16 bf16x8 __attribute__((ext_vector_type(8)));
typedef float  f32x4  __attribute__((ext_vector_type(4)));

static __device__ __forceinline__ unsigned short f2bf(float a) {
    union { float f; unsigned u; } x; x.f = a;
    return (unsigned short)((x.u + 0x7FFFu + ((x.u >> 16) & 1u)) >> 16);
}
static __device__ __forceinline__ unsigned f2bf_pack(float a, float b) {
    return (unsigned)f2bf(a) | ((unsigned)f2bf(b) << 16);
}
// pack two f32 -> bf16 pair, round-half-up (cheap, P in [0,1])
static __device__ __forceinline__ unsigned packbf(float a, float b) {
    union { float f; unsigned u; } x, y; x.f = a; y.f = b;
    return ((x.u + 0x8000u) >> 16) | ((y.u + 0x8000u) & 0xFFFF0000u);
}
static __device__ __forceinline__ bf16x8 as_bf16x8(uint4 u) {
    union { uint4 u; bf16x8 b; } x; x.u = u; return x.b;
}
static __device__ __forceinline__ bf16x8 lds_b128(const unsigned short* p) {
    return as_bf16x8(*(const uint4*)p);
}

// ---------------- prep: pack weights into MFMA B-fragment layout (bf16) ----------------
__global__ void prep_pack(const float* __restrict__ Wk,
                          const float* __restrict__ Wo,
                          unsigned short* __restrict__ wb) {
    int i = blockIdx.x * 256 + threadIdx.x;   // 0..36863
    if (i < WB2_USH) {
        int j = i & 7, l = (i >> 3) & 63, nk = i >> 9;     // nk = nt*3+ks
        int nt = nk / 3, ks = nk - nt * 3;
        int n = nt * 16 + (l & 15);
        int k = ks * 32 + ((l >> 4) << 3) + j;
        wb[i] = f2bf(Wk[n * 96 + k]);
    } else if (i < 36864) {
        int r = i - WB2_USH;
        int j = r & 7, l = (r >> 3) & 63, nk = r >> 9;
        int nt = nk / 3, ks = nk - nt * 3;
        int n = nt * 16 + (l & 15);
        int k = ks * 32 + ((l >> 4) << 3) + j;
        wb[i] = f2bf(Wo[n * 96 + k]);
    }
}

// ---------------- K_A: shift-gather + kqv GEMM + S + softmax -> att, v ----------------
// One block per b (grid 4096, 512 threads = 8 waves). Wave h = head h in attn phase.
__global__ __launch_bounds__(512) void k12a(
        const float* __restrict__ window,
        const float* __restrict__ b_kqv,
        const unsigned short* __restrict__ wb1,
        float* __restrict__ att_out,
        unsigned short* __restrict__ vbuf) {
    __shared__ unsigned short smem[SMEM_A_USH];
    __shared__ int wv2[512];

    const int t = threadIdx.x, b = blockIdx.x;
    const int w = t >> 6, l = t & 63;
    const int lr = l & 15, lg4 = l >> 4;

    // blanket-zero kq + tail (16000 dwords): K-dim pads must be 0, tail must be finite
    {
        unsigned* z = (unsigned*)(smem + KQ_OFF);
#pragma unroll
        for (int i = 0; i < 32; ++i) {
            int idx = t + i * 512;
            if (idx < 16000) z[idx] = 0;
        }
    }
    // gather + cvt 49 rows x 96 f32 (shifted-window input) -> xt bf16
    const int bimg = b >> 6, n = b & 63;
    unsigned short* xt = smem + XT_OFF;
    for (int idx = t; idx < 1176; idx += 512) {
        int r = idx / 24, c4 = idx % 24;
        int s = n * 49 + r;
        int y = s / 56, x = s - y * 56;
        int ys = y + 53; if (ys >= 56) ys -= 56;
        int xs = x + 53; if (xs >= 56) xs -= 56;
        int sn = (ys / 7) * 8 + (xs / 7);
        int sp = (ys % 7) * 7 + (xs % 7);
        float4 v = *((const float4*)(window + ((size_t)(bimg * 64 + sn) * 49 + sp) * 96) + c4);
        *(uint2*)&xt[r * 104 + c4 * 4] = make_uint2(f2bf_pack(v.x, v.y), f2bf_pack(v.z, v.w));
    }
    // window-id table for head w (faithful mask: m = (b*8+h) % 64); pad lanes -> -1
    {
        int val = -1;
        if (l < 49) {
            int m = ((b << 3) + w) & 63;
            int wi = m >> 3, wj = m & 7;
            int pi = l / 7, pj = l % 7;
            int y = wi * 7 + pi, x = wj * 7 + pj;
            int ys = y + 53; if (ys >= 56) ys -= 56;
            int xs = x + 53; if (xs >= 56) xs -= 56;
            val = (ys / 7) * 8 + (xs / 7);
        }
        wv2[w * 64 + l] = val;
    }
    __syncthreads();

    // ---- kqv GEMM: wave w -> m-tile (w&3), nt range (w>>2)*9 .. +8 ----
    {
        const int mt = w & 3, nh = w >> 2;
        bf16x8 a[3];
#pragma unroll
        for (int ks = 0; ks < 3; ++ks)
            a[ks] = lds_b128(&xt[(mt * 16 + lr) * 104 + ks * 32 + lg4 * 8]);

#pragma unroll
        for (int j = 0; j < 9; ++j) {
            int nt = nh * 9 + j;
            int col = nt * 16 + lr;          // 0..287
            float bias = b_kqv[col];
            f32x4 acc = {bias, bias, bias, bias};
#pragma unroll
            for (int ks = 0; ks < 3; ++ks) {
                bf16x8 bf = as_bf16x8(*(const uint4*)(wb1 + ((size_t)(nt * 3 + ks) * 64 + l) * 8));
                acc = __builtin_amdgcn_mfma_f32_16x16x32_bf16(a[ks], bf, acc, 0, 0, 0);
            }
            int seg = col / 96;              // uniform per nt (boundaries at 96,192)
            int cc = col - seg * 96;
            int h2 = cc / 12, d2 = cc - h2 * 12;
#pragma unroll
            for (int reg = 0; reg < 4; ++reg) {
                int R = mt * 16 + lg4 * 4 + reg;
                if (R < 49) {
                    unsigned short v = f2bf(acc[reg]);
                    if (seg == 0)      smem[KQ_OFF + (h2 * 49 + R) * 40 + d2] = v;
                    else if (seg == 1) smem[KQ_Q_OFF + (h2 * 49 + R) * 40 + d2] = v;
                    else               vbuf[((size_t)(b * 49 + R)) * 96 + cc] = v;
                }
            }
        }
    }
    __syncthreads();

    // ---- attention scores: wave w = head h ----
    const int h = w;
    const unsigned short* kb = smem + KQ_OFF + h * 1960;
    const unsigned short* qb = smem + KQ_Q_OFF + h * 1960;
    const int* wvh = wv2 + h * 64;

    // S = Q * K^T  (rows/cols >=49 are garbage; neutralized by mask / discarded)
    f32x4 sc[4][4];
    {
        bf16x8 qa[4];
#pragma unroll
        for (int mt = 0; mt < 4; ++mt)
            qa[mt] = lds_b128(&qb[(mt * 16 + lr) * 40 + lg4 * 8]);
#pragma unroll
        for (int nt = 0; nt < 4; ++nt) {
            bf16x8 kf = lds_b128(&kb[(nt * 16 + lr) * 40 + lg4 * 8]);
#pragma unroll
            for (int mt = 0; mt < 4; ++mt) {
                f32x4 zz = {0.f, 0.f, 0.f, 0.f};
                sc[mt][nt] = __builtin_amdgcn_mfma_f32_16x16x32_bf16(qa[mt], kf, zz, 0, 0, 0);
            }
        }
    }

    int wvr[4], wvm[4][4];
#pragma unroll
    for (int nt = 0; nt < 4; ++nt) wvr[nt] = wvh[nt * 16 + lr];
#pragma unroll
    for (int mt = 0; mt < 4; ++mt)
#pragma unroll
        for (int reg = 0; reg < 4; ++reg) wvm[mt][reg] = wvh[mt * 16 + lg4 * 4 + reg];

    const float scale = 0.2886751345948129f;   // 1/sqrt(12)
    float mxv[4][4], sm[4][4];
#pragma unroll
    for (int mt = 0; mt < 4; ++mt)
#pragma unroll
        for (int reg = 0; reg < 4; ++reg) {
            float mx = -3.0e38f;
#pragma unroll
            for (int nt = 0; nt < 4; ++nt) {
                float v = sc[mt][nt][reg] * scale;
                if (wvr[nt] != wvm[mt][reg]) v += NEGV;
                sc[mt][nt][reg] = v;
                mx = fmaxf(mx, v);
            }
            mxv[mt][reg] = mx;
        }
#pragma unroll
    for (int mt = 0; mt < 4; ++mt)
#pragma unroll
        for (int reg = 0; reg < 4; ++reg) {
            float mx = mxv[mt][reg];
            mx = fmaxf(mx, __shfl_xor(mx, 1));
            mx = fmaxf(mx, __shfl_xor(mx, 2));
            mx = fmaxf(mx, __shfl_xor(mx, 4));
            mx = fmaxf(mx, __shfl_xor(mx, 8));
            mxv[mt][reg] = mx;
        }
#pragma unroll
    for (int mt = 0; mt < 4; ++mt)
#pragma unroll
        for (int reg = 0; reg < 4; ++reg) {
            float s = 0.f;
#pragma unroll
            for (int nt = 0; nt < 4; ++nt) {
                float e = __expf(sc[mt][nt][reg] - mxv[mt][reg]);
                sc[mt][nt][reg] = e;
                s += e;
            }
            sm[mt][reg] = s;
        }
#pragma unroll
    for (int mt = 0; mt < 4; ++mt)
#pragma unroll
        for (int reg = 0; reg < 4; ++reg) {
            float s = sm[mt][reg];
            s += __shfl_xor(s, 1);
            s += __shfl_xor(s, 2);
            s += __shfl_xor(s, 4);
            s += __shfl_xor(s, 8);
            sm[mt][reg] = 1.0f / s;
        }

    // write att (f32, masked)
    float* ab = att_out + ((size_t)((b << 3) + h)) * 2401;
#pragma unroll
    for (int mt = 0; mt < 4; ++mt)
#pragma unroll
        for (int reg = 0; reg < 4; ++reg) {
            int m = mt * 16 + lg4 * 4 + reg;
            float inv = sm[mt][reg];
#pragma unroll
            for (int nt = 0; nt < 4; ++nt) {
                int r = nt * 16 + lr;
                if (m < 49 && r < 49) ab[m * 49 + r] = sc[mt][nt][reg] * inv;
            }
        }
}

// ---------------- K_B: PV (att re-read as A-frags) + output projection + inverse shift ----------------
// One block per b (grid 4096, 512 threads = 8 waves). Wave w = head w in PV phase.
__global__ __launch_bounds__(512) void k34(
        const float* __restrict__ att,
        const unsigned short* __restrict__ vbuf,
        const unsigned short* __restrict__ wb2,
        const float* __restrict__ b_out,
        float* __restrict__ out) {
    __shared__ unsigned short vt[100 * 72];      // V^T [d][r], zero-padded
    __shared__ unsigned short ostage[64 * 104];  // O bf16 [m][96+pad]

    const int t = threadIdx.x, b = blockIdx.x;
    const int w = t >> 6, l = t & 63;
    const int lr = l & 15, lg4 = l >> 4;

    // zero vt (3600 dwords) — cols 49..71 and rows 96..99 MUST be 0/finite
    {
        unsigned* z = (unsigned*)vt;
#pragma unroll
        for (int i = 0; i < 8; ++i) {
            int idx = t + i * 512;
            if (idx < 3600) z[idx] = 0;
        }
    }
    __syncthreads();
    // stage V^T: vbuf[b] is [49][96] bf16 = 4704 ushorts = 588 uint4
    for (int i = t; i < 588; i += 512) {
        uint4 v = *((const uint4*)(vbuf + (size_t)b * 4704) + i);
        int r = i / 12, c0 = (i % 12) * 8;
        const unsigned short* pv = (const unsigned short*)&v;
#pragma unroll
        for (int e = 0; e < 8; ++e) vt[(c0 + e) * 72 + r] = pv[e];
    }
    __syncthreads();

    // ---- PV: wave w = head w.  O = P * V ----
    const float* pab = att + (size_t)((b << 3) + w) * 2401;
    f32x4 oc[4];
#pragma unroll
    for (int mt = 0; mt < 4; ++mt) oc[mt] = (f32x4){0.f, 0.f, 0.f, 0.f};

#pragma unroll
    for (int mt = 0; mt < 4; ++mt) {
        int mrow = mt * 16 + lr; if (mrow > 48) mrow = 48;   // clamp pad rows
        const float* prow = pab + mrow * 49;
#pragma unroll
        for (int ks = 0; ks < 2; ++ks) {
            int r0 = ks * 32 + lg4 * 8;
            float pv[8];
#pragma unroll
            for (int j = 0; j < 8; ++j) {
                int r = r0 + j;
                pv[j] = (r < 49) ? prow[r] : 0.0f;
            }
            uint4 pu = make_uint4(packbf(pv[0], pv[1]), packbf(pv[2], pv[3]),
                                  packbf(pv[4], pv[5]), packbf(pv[6], pv[7]));
            bf16x8 pa = as_bf16x8(pu);
            bf16x8 vf = lds_b128(&vt[(w * 12 + lr) * 72 + r0]);
            oc[mt] = __builtin_amdgcn_mfma_f32_16x16x32_bf16(pa, vf, oc[mt], 0, 0, 0);
        }
    }
    // O -> ostage (all rows 0..63 written; cols masked to this head's 12)
#pragma unroll
    for (int mt = 0; mt < 4; ++mt)
#pragma unroll
        for (int reg = 0; reg < 4; ++reg) {
            if (lr < 12)
                ostage[(mt * 16 + lg4 * 4 + reg) * 104 + w * 12 + lr] = f2bf(oc[mt][reg]);
        }
    __syncthreads();

    // ---- output projection + INVERSE CYCLE SHIFT scatter ----
    // Reference: cycle_shift(proj, 7, -4) = window_to_image (PROPER partition:
    // window n, patch m -> image (Yi,Xi) = ((n/8)*7 + m/7, (n%8)*7 + m%7)),
    // roll(-4,-4) (-> (Yi-4, Xi-4) mod 56), then NAIVE reshape (final flat row
    // = Yo*56+Xo). Round-8 bug: used naive s=n*49+m for the pre-roll coords.
    {
        const int bimg = b >> 6, n = b & 63;
        const int mt = w & 3, nh = w >> 2;
        bf16x8 a[3];
#pragma unroll
        for (int ks = 0; ks < 3; ++ks)
            a[ks] = lds_b128(&ostage[(mt * 16 + lr) * 104 + ks * 32 + lg4 * 8]);

        // per-reg output rows (proper partition -> roll(-4) -> naive flat)
        size_t orow[4];
        const int wi = n >> 3, wj = n & 7;
#pragma unroll
        for (int reg = 0; reg < 4; ++reg) {
            int m = mt * 16 + lg4 * 4 + reg;
            if (m > 48) m = 48;
            int pi = m / 7, pj = m - pi * 7;
            int Yi = wi * 7 + pi, Xi = wj * 7 + pj;
            int Yo = Yi - 4; if (Yo < 0) Yo += 56;
            int Xo = Xi - 4; if (Xo < 0) Xo += 56;
            orow[reg] = (size_t)(bimg * 3136 + Yo * 56 + Xo) * 96;
        }

#pragma unroll
        for (int j = 0; j < 3; ++j) {
            int nt = nh * 3 + j;
            int col = nt * 16 + lr;
            float bias = b_out[col];
            f32x4 acc = {bias, bias, bias, bias};
#pragma unroll
            for (int ks = 0; ks < 3; ++ks) {
                bf16x8 bf = as_bf16x8(*(const uint4*)(wb2 + (size_t)((nt * 3 + ks) * 64 + l) * 8));
                acc = __builtin_amdgcn_mfma_f32_16x16x32_bf16(a[ks], bf, acc, 0, 0, 0);
            }
#pragma unroll
            for (int reg = 0; reg < 4; ++reg) {
                int m = mt * 16 + lg4 * 4 + reg;
                if (m < 49)
                    out[orow[reg] + col] = acc[reg];
            }
        }
    }
}

extern "C" void kernel_launch(void* const* d_in, const int* in_sizes, int n_in,
                              void* d_out, int out_size, void* d_ws, size_t ws_size,
                              hipStream_t stream) {
    const float* window = (const float*)d_in[0];
    const float* W_kqv  = (const float*)d_in[1];
    const float* b_kqv  = (const float*)d_in[2];
    const float* W_out  = (const float*)d_in[3];
    const float* b_out  = (const float*)d_in[4];

    float* out = (float*)d_out;
    float* att = out + OUT_ELEMS;

    unsigned short* wb   = (unsigned short*)d_ws;
    unsigned short* vbuf = (unsigned short*)((char*)d_ws + VBUF_OFF_B);

    prep_pack<<<144, 256, 0, stream>>>(W_kqv, W_out, wb);
    k12a<<<4096, 512, 0, stream>>>(window, b_kqv, wb, att, vbuf);
    k34<<<4096, 512, 0, stream>>>(att, vbuf, wb + WB2_USH, b_out, out);
}

// Round 10
// 245.012 us; speedup vs baseline: 1.3554x; 1.3554x over previous
//
#include <hip/hip_runtime.h>
#include <hip/hip_bf16.h>

// Problem constants
#define NEGV  (-1000000.0f)
#define OUT_ELEMS   19267584     // 64*64*49*96 (att follows in d_out)

// ws layout (bytes): packed bf16 B-fragments only: Wb1 27648 ush, Wb2 9216 ush
#define WB2_USH     27648

// fused-kernel LDS (ushort offsets)
//  xt [64][104] 6656   (overlaid by ostage [64][104] after GEMM phase)
//  kq [2][8][49][20] 15680   (K=16 padded; stride 20 ush = 40B, 8B-aligned, 2-way banks)
//  vt [100][72] 7200   (V^T [d][r], stride 144B 16B-aligned; pads zeroed)
#define XT_OFF     0
#define OST_OFF    0
#define KQ_OFF     6656
#define KQ_Q_OFF   (KQ_OFF + 7840)
#define VT_OFF     (KQ_OFF + 15680)
#define SMEM_USH   (6656 + 15680 + 7200)

typedef __bf16 bf16x4 __attribute__((ext_vector_type(4)));
typedef __bf16 bf16x8 __attribute__((ext_vector_type(8)));
typedef float  f32x4  __attribute__((ext_vector_type(4)));

static __device__ __forceinline__ unsigned short f2bf(float a) {
    union { float f; unsigned u; } x; x.f = a;
    return (unsigned short)((x.u + 0x7FFFu + ((x.u >> 16) & 1u)) >> 16);
}
static __device__ __forceinline__ unsigned f2bf_pack(float a, float b) {
    return (unsigned)f2bf(a) | ((unsigned)f2bf(b) << 16);
}
// pack two f32 -> bf16 pair, round-half-up (P in [0,1], cheap)
static __device__ __forceinline__ unsigned packbf(float a, float b) {
    union { float f; unsigned u; } x, y; x.f = a; y.f = b;
    return ((x.u + 0x8000u) >> 16) | ((y.u + 0x8000u) & 0xFFFF0000u);
}
static __device__ __forceinline__ bf16x8 as_bf16x8(uint4 u) {
    union { uint4 u; bf16x8 b; } x; x.u = u; return x.b;
}
static __device__ __forceinline__ bf16x4 as_bf16x4(uint2 u) {
    union { uint2 u; bf16x4 b; } x; x.u = u; return x.b;
}
static __device__ __forceinline__ bf16x8 lds_b128(const unsigned short* p) {
    return as_bf16x8(*(const uint4*)p);
}
static __device__ __forceinline__ bf16x4 lds_b64(const unsigned short* p) {
    return as_bf16x4(*(const uint2*)p);
}
// K=16 bf16 MFMA via inline asm (only K=32 builtins are guide-verified on gfx950;
// v_mfma_f32_16x16x16_bf16 is in cdna4_isa.md §10: A=2 B=2 C/D=4 regs)
static __device__ __forceinline__ void mfma16(f32x4& c, bf16x4 a, bf16x4 b) {
    asm("v_mfma_f32_16x16x16_bf16 %0, %1, %2, %0" : "+v"(c) : "v"(a), "v"(b));
}

// ---------------- prep: pack weights into MFMA B-fragment layout (bf16) ----------------
__global__ void prep_pack(const float* __restrict__ Wk,
                          const float* __restrict__ Wo,
                          unsigned short* __restrict__ wb) {
    int i = blockIdx.x * 256 + threadIdx.x;   // 0..36863
    if (i < WB2_USH) {
        int j = i & 7, l = (i >> 3) & 63, nk = i >> 9;     // nk = nt*3+ks
        int nt = nk / 3, ks = nk - nt * 3;
        int n = nt * 16 + (l & 15);
        int k = ks * 32 + ((l >> 4) << 3) + j;
        wb[i] = f2bf(Wk[n * 96 + k]);
    } else if (i < 36864) {
        int r = i - WB2_USH;
        int j = r & 7, l = (r >> 3) & 63, nk = r >> 9;
        int nt = nk / 3, ks = nk - nt * 3;
        int n = nt * 16 + (l & 15);
        int k = ks * 32 + ((l >> 4) << 3) + j;
        wb[i] = f2bf(Wo[n * 96 + k]);
    }
}

// ---------------- fused: gather + kqv GEMM + S + softmax + att + PV + proj + scatter ----
// One block per b (grid 4096, 512 threads = 8 waves, 2 blocks/CU).
__global__ __launch_bounds__(512, 4) void kfused(
        const float* __restrict__ window,
        const float* __restrict__ b_kqv,
        const unsigned short* __restrict__ wb1,
        const unsigned short* __restrict__ wb2,
        const float* __restrict__ b_out,
        float* __restrict__ att_out,
        float* __restrict__ out) {
    __shared__ unsigned short smem[SMEM_USH];
    __shared__ int wv2[512];

    const int t = threadIdx.x, b = blockIdx.x;
    const int w = t >> 6, l = t & 63;
    const int lr = l & 15, lg4 = l >> 4;
    const int bimg = b >> 6, n = b & 63;

    // ---- phase 0: blanket-zero kq+vt (every MFMA-reachable LDS elem must be finite;
    // 0*NaN=NaN — masking outputs does not sanitize the K-dim), gather xt, wv table ----
    {
        unsigned* z = (unsigned*)(smem + KQ_OFF);
#pragma unroll
        for (int i = 0; i < 23; ++i) {
            int idx = t + i * 512;
            if (idx < 11440) z[idx] = 0;     // (15680+7200)/2 dwords
        }
    }
    unsigned short* xt = smem + XT_OFF;
    for (int idx = t; idx < 1176; idx += 512) {
        int r = idx / 24, c4 = idx % 24;
        int s = n * 49 + r;
        int y = s / 56, x = s - y * 56;
        int ys = y + 53; if (ys >= 56) ys -= 56;
        int xs = x + 53; if (xs >= 56) xs -= 56;
        int sn = (ys / 7) * 8 + (xs / 7);
        int sp = (ys % 7) * 7 + (xs % 7);
        float4 v = *((const float4*)(window + ((size_t)(bimg * 64 + sn) * 49 + sp) * 96) + c4);
        *(uint2*)&xt[r * 104 + c4 * 4] = make_uint2(f2bf_pack(v.x, v.y), f2bf_pack(v.z, v.w));
    }
    {
        int val = -1;
        if (l < 49) {
            int m = ((b << 3) + w) & 63;     // faithful mask index
            int wi = m >> 3, wj = m & 7;
            int pi = l / 7, pj = l % 7;
            int y = wi * 7 + pi, x = wj * 7 + pj;
            int ys = y + 53; if (ys >= 56) ys -= 56;
            int xs = x + 53; if (xs >= 56) xs -= 56;
            val = (ys / 7) * 8 + (xs / 7);
        }
        wv2[w * 64 + l] = val;
    }
    __syncthreads();

    // ---- phase 1: kqv GEMM (K=32). k,q -> kq LDS; v -> vt LDS (transposed) ----
    {
        const int mt = w & 3, nh = w >> 2;
        bf16x8 a[3];
#pragma unroll
        for (int ks = 0; ks < 3; ++ks)
            a[ks] = lds_b128(&xt[(mt * 16 + lr) * 104 + ks * 32 + lg4 * 8]);

#pragma unroll
        for (int j = 0; j < 9; ++j) {
            int nt = nh * 9 + j;
            int col = nt * 16 + lr;          // 0..287
            float bias = b_kqv[col];
            f32x4 acc = {bias, bias, bias, bias};
#pragma unroll
            for (int ks = 0; ks < 3; ++ks) {
                bf16x8 bf = as_bf16x8(*(const uint4*)(wb1 + ((size_t)(nt * 3 + ks) * 64 + l) * 8));
                acc = __builtin_amdgcn_mfma_f32_16x16x32_bf16(a[ks], bf, acc, 0, 0, 0);
            }
            int seg = col / 96;              // uniform per nt
            int cc = col - seg * 96;
            int h2 = cc / 12, d2 = cc - h2 * 12;
#pragma unroll
            for (int reg = 0; reg < 4; ++reg) {
                int R = mt * 16 + lg4 * 4 + reg;
                if (R < 49) {
                    unsigned short v = f2bf(acc[reg]);
                    if (seg == 0)      smem[KQ_OFF + (h2 * 49 + R) * 20 + d2] = v;
                    else if (seg == 1) smem[KQ_Q_OFF + (h2 * 49 + R) * 20 + d2] = v;
                    else               smem[VT_OFF + cc * 72 + R] = v;
                }
            }
        }
    }
    __syncthreads();

    // ---- phase 2: per-wave head h. S = Q*K^T via K=16 MFMA ----
    const int h = w;
    const unsigned short* kb = smem + KQ_OFF + h * 980;
    const unsigned short* qb = smem + KQ_Q_OFF + h * 980;
    const unsigned short* vb = smem + VT_OFF;
    const int* wvh = wv2 + h * 64;

    f32x4 sc[4][4];
    {
        bf16x4 qa[4];
#pragma unroll
        for (int mt = 0; mt < 4; ++mt)
            qa[mt] = lds_b64(&qb[(mt * 16 + lr) * 20 + lg4 * 4]);
#pragma unroll
        for (int nt = 0; nt < 4; ++nt) {
            bf16x4 kf = lds_b64(&kb[(nt * 16 + lr) * 20 + lg4 * 4]);
#pragma unroll
            for (int mt = 0; mt < 4; ++mt) {
                sc[mt][nt] = (f32x4){0.f, 0.f, 0.f, 0.f};
                mfma16(sc[mt][nt], qa[mt], kf);
            }
        }
    }

    int wvr[4], wvm[4][4];
#pragma unroll
    for (int nt = 0; nt < 4; ++nt) wvr[nt] = wvh[nt * 16 + lr];
#pragma unroll
    for (int mt = 0; mt < 4; ++mt)
#pragma unroll
        for (int reg = 0; reg < 4; ++reg) wvm[mt][reg] = wvh[mt * 16 + lg4 * 4 + reg];

    const float scale = 0.2886751345948129f;   // 1/sqrt(12)
    float mxv[4][4], sm[4][4];
#pragma unroll
    for (int mt = 0; mt < 4; ++mt)
#pragma unroll
        for (int reg = 0; reg < 4; ++reg) {
            float mx = -3.0e38f;
#pragma unroll
            for (int nt = 0; nt < 4; ++nt) {
                float v = sc[mt][nt][reg] * scale;
                if (wvr[nt] != wvm[mt][reg]) v += NEGV;
                sc[mt][nt][reg] = v;
                mx = fmaxf(mx, v);
            }
            mxv[mt][reg] = mx;
        }
#pragma unroll
    for (int mt = 0; mt < 4; ++mt)
#pragma unroll
        for (int reg = 0; reg < 4; ++reg) {
            float mx = mxv[mt][reg];
            mx = fmaxf(mx, __shfl_xor(mx, 1));
            mx = fmaxf(mx, __shfl_xor(mx, 2));
            mx = fmaxf(mx, __shfl_xor(mx, 4));
            mx = fmaxf(mx, __shfl_xor(mx, 8));
            mxv[mt][reg] = mx;
        }
#pragma unroll
    for (int mt = 0; mt < 4; ++mt)
#pragma unroll
        for (int reg = 0; reg < 4; ++reg) {
            float s = 0.f;
#pragma unroll
            for (int nt = 0; nt < 4; ++nt) {
                float e = __expf(sc[mt][nt][reg] - mxv[mt][reg]);
                sc[mt][nt][reg] = e;
                s += e;
            }
            sm[mt][reg] = s;
        }
#pragma unroll
    for (int mt = 0; mt < 4; ++mt)
#pragma unroll
        for (int reg = 0; reg < 4; ++reg) {
            float s = sm[mt][reg];
            s += __shfl_xor(s, 1);
            s += __shfl_xor(s, 2);
            s += __shfl_xor(s, 4);
            s += __shfl_xor(s, 8);
            sm[mt][reg] = 1.0f / s;
        }

    // write att (f32, masked; coalesced 64B runs per 16-lane group)
    float* ab = att_out + ((size_t)((b << 3) + h)) * 2401;
#pragma unroll
    for (int mt = 0; mt < 4; ++mt)
#pragma unroll
        for (int reg = 0; reg < 4; ++reg) {
            int m = mt * 16 + lg4 * 4 + reg;
            float inv = sm[mt][reg];
#pragma unroll
            for (int nt = 0; nt < 4; ++nt) {
                int r = nt * 16 + lr;
                if (m < 49 && r < 49) ab[m * 49 + r] = sc[mt][nt][reg] * inv;
            }
        }

    // drain the att stores, then read back this wave's own P (L1/L2 hit)
    asm volatile("s_waitcnt vmcnt(0)" ::: "memory");

    // ---- PV: O = P * V (K=32), A-frags re-read from att, B from vt LDS ----
    f32x4 oc[4];
#pragma unroll
    for (int mt = 0; mt < 4; ++mt) oc[mt] = (f32x4){0.f, 0.f, 0.f, 0.f};

#pragma unroll
    for (int mt = 0; mt < 4; ++mt) {
        int mrow = mt * 16 + lr; if (mrow > 48) mrow = 48;   // clamp pad rows
        const float* prow = ab + mrow * 49;
#pragma unroll
        for (int ks = 0; ks < 2; ++ks) {
            int r0 = ks * 32 + lg4 * 8;
            float p[8];
            if (ks == 0) {                     // r = 8*lg4..+7 <= 31, all valid
#pragma unroll
                for (int j = 0; j < 8; ++j) p[j] = prow[r0 + j];
            } else {
                if (lg4 <= 1) {                // r = 32..47, all valid
#pragma unroll
                    for (int j = 0; j < 8; ++j) p[j] = prow[r0 + j];
                } else if (lg4 == 2) {         // r = 48..55: only r=48 valid
                    p[0] = prow[48];
#pragma unroll
                    for (int j = 1; j < 8; ++j) p[j] = 0.f;
                } else {                       // r >= 56: all pad
#pragma unroll
                    for (int j = 0; j < 8; ++j) p[j] = 0.f;
                }
            }
            uint4 pu = make_uint4(packbf(p[0], p[1]), packbf(p[2], p[3]),
                                  packbf(p[4], p[5]), packbf(p[6], p[7]));
            bf16x8 pa = as_bf16x8(pu);
            bf16x8 vf = lds_b128(&vb[(h * 12 + lr) * 72 + r0]);
            oc[mt] = __builtin_amdgcn_mfma_f32_16x16x32_bf16(pa, vf, oc[mt], 0, 0, 0);
        }
    }
    // O -> ostage bf16 (overlays dead xt region)
    unsigned short* ost = smem + OST_OFF;
#pragma unroll
    for (int mt = 0; mt < 4; ++mt)
#pragma unroll
        for (int reg = 0; reg < 4; ++reg) {
            if (lr < 12)
                ost[(mt * 16 + lg4 * 4 + reg) * 104 + h * 12 + lr] = f2bf(oc[mt][reg]);
        }
    __syncthreads();

    // ---- phase 3: output projection (K=32) + inverse-cycle-shift scatter ----
    // cycle_shift(proj, 7, -4): PROPER window partition (window n, patch m ->
    // (Yi,Xi)=((n/8)*7+m/7,(n%8)*7+m%7)) -> roll(-4,-4) -> NAIVE reshape.
    {
        const int mt = w & 3, nh = w >> 2;
        bf16x8 a[3];
#pragma unroll
        for (int ks = 0; ks < 3; ++ks)
            a[ks] = lds_b128(&ost[(mt * 16 + lr) * 104 + ks * 32 + lg4 * 8]);

        size_t orow[4];
        const int wi = n >> 3, wj = n & 7;
#pragma unroll
        for (int reg = 0; reg < 4; ++reg) {
            int m = mt * 16 + lg4 * 4 + reg;
            if (m > 48) m = 48;
            int pi = m / 7, pj = m - pi * 7;
            int Yi = wi * 7 + pi, Xi = wj * 7 + pj;
            int Yo = Yi - 4; if (Yo < 0) Yo += 56;
            int Xo = Xi - 4; if (Xo < 0) Xo += 56;
            orow[reg] = (size_t)(bimg * 3136 + Yo * 56 + Xo) * 96;
        }

#pragma unroll
        for (int j = 0; j < 3; ++j) {
            int nt = nh * 3 + j;
            int col = nt * 16 + lr;
            float bias = b_out[col];
            f32x4 acc = {bias, bias, bias, bias};
#pragma unroll
            for (int ks = 0; ks < 3; ++ks) {
                bf16x8 bf = as_bf16x8(*(const uint4*)(wb2 + (size_t)((nt * 3 + ks) * 64 + l) * 8));
                acc = __builtin_amdgcn_mfma_f32_16x16x32_bf16(a[ks], bf, acc, 0, 0, 0);
            }
#pragma unroll
            for (int reg = 0; reg < 4; ++reg) {
                int m = mt * 16 + lg4 * 4 + reg;
                if (m < 49)
                    out[orow[reg] + col] = acc[reg];
            }
        }
    }
}

extern "C" void kernel_launch(void* const* d_in, const int* in_sizes, int n_in,
                              void* d_out, int out_size, void* d_ws, size_t ws_size,
                              hipStream_t stream) {
    const float* window = (const float*)d_in[0];
    const float* W_kqv  = (const float*)d_in[1];
    const float* b_kqv  = (const float*)d_in[2];
    const float* W_out  = (const float*)d_in[3];
    const float* b_out  = (const float*)d_in[4];

    float* out = (float*)d_out;
    float* att = out + OUT_ELEMS;

    unsigned short* wb = (unsigned short*)d_ws;

    prep_pack<<<144, 256, 0, stream>>>(W_kqv, W_out, wb);
    kfused<<<4096, 512, 0, stream>>>(window, b_kqv, wb, wb + WB2_USH, b_out, att, out);
}

// Round 11
// 193.262 us; speedup vs baseline: 1.7184x; 1.2678x over previous
//
#include <hip/hip_runtime.h>
#include <hip/hip_bf16.h>

// Problem constants
#define NEGV  (-1000000.0f)
#define OUT_ELEMS   19267584     // 64*64*49*96 (att follows in d_out)

// ws layout (bytes): packed bf16 B-fragments only: Wb1 27648 ush, Wb2 9216 ush
#define WB2_USH     27648

// LDS layout (ushort offsets), time-multiplexed:
//  region A [0..22336): xt [64][104]=6656 + kq [784][20]=15680  (phases 0-2)
//                       pbuf [8][49][52]=20384                  (PV, post-barrier)
//                       ost [64][104]=6656                      (phase 3, post-barrier)
//  vt [100][56]=5600 at 22336  (V^T [d][r]; rows 96..99 zeroed, col 48 = V[48][d])
#define XT_OFF     0
#define KQ_OFF     6656
#define KQ_Q_OFF   (KQ_OFF + 7840)
#define PB_OFF     0
#define OST_OFF    0
#define VT_OFF     22336
#define SMEM_USH   (22336 + 5600)

typedef __bf16 bf16x4 __attribute__((ext_vector_type(4)));
typedef __bf16 bf16x8 __attribute__((ext_vector_type(8)));
typedef float  f32x4  __attribute__((ext_vector_type(4)));

static __device__ __forceinline__ unsigned short f2bf(float a) {
    union { float f; unsigned u; } x; x.f = a;
    return (unsigned short)((x.u + 0x7FFFu + ((x.u >> 16) & 1u)) >> 16);
}
static __device__ __forceinline__ unsigned f2bf_pack(float a, float b) {
    return (unsigned)f2bf(a) | ((unsigned)f2bf(b) << 16);
}
static __device__ __forceinline__ float bf2f(unsigned s) {
    union { unsigned u; float f; } v; v.u = s << 16; return v.f;
}
static __device__ __forceinline__ bf16x8 as_bf16x8(uint4 u) {
    union { uint4 u; bf16x8 b; } x; x.u = u; return x.b;
}
static __device__ __forceinline__ bf16x4 as_bf16x4(uint2 u) {
    union { uint2 u; bf16x4 b; } x; x.u = u; return x.b;
}
static __device__ __forceinline__ bf16x8 lds_b128(const unsigned short* p) {
    return as_bf16x8(*(const uint4*)p);
}
static __device__ __forceinline__ bf16x4 lds_b64(const unsigned short* p) {
    return as_bf16x4(*(const uint2*)p);
}
// K=16 bf16 MFMA via inline asm (verified working in round 10)
static __device__ __forceinline__ void mfma16(f32x4& c, bf16x4 a, bf16x4 b) {
    asm("v_mfma_f32_16x16x16_bf16 %0, %1, %2, %0" : "+v"(c) : "v"(a), "v"(b));
}

// ---------------- prep: pack weights into MFMA B-fragment layout (bf16) ----------------
__global__ void prep_pack(const float* __restrict__ Wk,
                          const float* __restrict__ Wo,
                          unsigned short* __restrict__ wb) {
    int i = blockIdx.x * 256 + threadIdx.x;   // 0..36863
    if (i < WB2_USH) {
        int j = i & 7, l = (i >> 3) & 63, nk = i >> 9;     // nk = nt*3+ks
        int nt = nk / 3, ks = nk - nt * 3;
        int n = nt * 16 + (l & 15);
        int k = ks * 32 + ((l >> 4) << 3) + j;
        wb[i] = f2bf(Wk[n * 96 + k]);
    } else if (i < 36864) {
        int r = i - WB2_USH;
        int j = r & 7, l = (r >> 3) & 63, nk = r >> 9;
        int nt = nk / 3, ks = nk - nt * 3;
        int n = nt * 16 + (l & 15);
        int k = ks * 32 + ((l >> 4) << 3) + j;
        wb[i] = f2bf(Wo[n * 96 + k]);
    }
}

// ---------------- fused: gather + kqv GEMM + S + softmax + att + PV + proj + scatter ----
// One block per b (grid 4096, 512 threads = 8 waves, 2 blocks/CU).
__global__ __launch_bounds__(512, 4) void kfused(
        const float* __restrict__ window,
        const float* __restrict__ b_kqv,
        const unsigned short* __restrict__ wb1,
        const unsigned short* __restrict__ wb2,
        const float* __restrict__ b_out,
        float* __restrict__ att_out,
        float* __restrict__ out) {
    __shared__ unsigned short smem[SMEM_USH];
    __shared__ signed char wv2[512];

    const int t = threadIdx.x, b = blockIdx.x;
    const int w = t >> 6, l = t & 63;
    const int lr = l & 15, lg4 = l >> 4;
    const int bimg = b >> 6, n = b & 63;

    // ---- phase 0: selective zero (K-dim pads MUST be 0: 0*NaN=NaN; rows are safe
    // garbage since MFMA rows are independent and outputs masked) ----
    //   kq pad cols 12..15 -> dwords row*10+{6,7}, rows 0..783  (1568 dwords)
    //   vt rows 96..99 (B-frag overread rows for lr>=12)        (112 dwords)
    {
        unsigned* zb = (unsigned*)smem;
#pragma unroll
        for (int i0 = 0; i0 < 4; ++i0) {
            int i = t + i0 * 512;
            if (i < 1568) {
                int row = i >> 1;
                zb[KQ_OFF / 2 + row * 10 + 6 + (i & 1)] = 0;
            } else if (i < 1680) {
                zb[VT_OFF / 2 + 96 * 28 + (i - 1568)] = 0;
            }
        }
    }
    // gather + cvt 49 rows x 96 f32 (shifted-window input) -> xt bf16
    unsigned short* xt = smem + XT_OFF;
    for (int idx = t; idx < 1176; idx += 512) {
        int r = idx / 24, c4 = idx % 24;
        int s = n * 49 + r;
        int y = s / 56, x = s - y * 56;
        int ys = y + 53; if (ys >= 56) ys -= 56;
        int xs = x + 53; if (xs >= 56) xs -= 56;
        int sn = (ys / 7) * 8 + (xs / 7);
        int sp = (ys % 7) * 7 + (xs % 7);
        float4 v = *((const float4*)(window + ((size_t)(bimg * 64 + sn) * 49 + sp) * 96) + c4);
        *(uint2*)&xt[r * 104 + c4 * 4] = make_uint2(f2bf_pack(v.x, v.y), f2bf_pack(v.z, v.w));
    }
    // window-id table (faithful mask: m = (b*8+h) % 64); pad lanes -> -1
    {
        int val = -1;
        if (l < 49) {
            int m = ((b << 3) + w) & 63;
            int wi = m >> 3, wj = m & 7;
            int pi = l / 7, pj = l % 7;
            int y = wi * 7 + pi, x = wj * 7 + pj;
            int ys = y + 53; if (ys >= 56) ys -= 56;
            int xs = x + 53; if (xs >= 56) xs -= 56;
            val = (ys / 7) * 8 + (xs / 7);
        }
        wv2[w * 64 + l] = (signed char)val;
    }
    __syncthreads();

    // ---- phase 1: kqv GEMM (K=32). k,q -> kq LDS; v -> vt LDS (transposed) ----
    {
        const int mt = w & 3, nh = w >> 2;
        bf16x8 a[3];
#pragma unroll
        for (int ks = 0; ks < 3; ++ks)
            a[ks] = lds_b128(&xt[(mt * 16 + lr) * 104 + ks * 32 + lg4 * 8]);

#pragma unroll
        for (int j = 0; j < 9; ++j) {
            int nt = nh * 9 + j;
            int col = nt * 16 + lr;          // 0..287
            float bias = b_kqv[col];
            f32x4 acc = {bias, bias, bias, bias};
#pragma unroll
            for (int ks = 0; ks < 3; ++ks) {
                bf16x8 bf = as_bf16x8(*(const uint4*)(wb1 + ((size_t)(nt * 3 + ks) * 64 + l) * 8));
                acc = __builtin_amdgcn_mfma_f32_16x16x32_bf16(a[ks], bf, acc, 0, 0, 0);
            }
            int seg = col / 96;              // uniform per nt
            int cc = col - seg * 96;
            int h2 = cc / 12, d2 = cc - h2 * 12;
#pragma unroll
            for (int reg = 0; reg < 4; ++reg) {
                int R = mt * 16 + lg4 * 4 + reg;
                if (R < 49) {
                    unsigned short v = f2bf(acc[reg]);
                    if (seg == 0)      smem[KQ_OFF + (h2 * 49 + R) * 20 + d2] = v;
                    else if (seg == 1) smem[KQ_Q_OFF + (h2 * 49 + R) * 20 + d2] = v;
                    else               smem[VT_OFF + cc * 56 + R] = v;
                }
            }
        }
    }
    __syncthreads();

    // ---- phase 2: per-wave head h. S = Q*K^T via K=16 MFMA ----
    const int h = w;
    const unsigned short* kb = smem + KQ_OFF + h * 980;
    const unsigned short* qb = smem + KQ_Q_OFF + h * 980;
    const unsigned short* vt = smem + VT_OFF;
    const signed char* wvh = wv2 + h * 64;

    f32x4 sc[4][4];
    {
        bf16x4 qa[4];
#pragma unroll
        for (int mt = 0; mt < 4; ++mt)
            qa[mt] = lds_b64(&qb[(mt * 16 + lr) * 20 + lg4 * 4]);
#pragma unroll
        for (int nt = 0; nt < 4; ++nt) {
            bf16x4 kf = lds_b64(&kb[(nt * 16 + lr) * 20 + lg4 * 4]);
#pragma unroll
            for (int mt = 0; mt < 4; ++mt) {
                sc[mt][nt] = (f32x4){0.f, 0.f, 0.f, 0.f};
                mfma16(sc[mt][nt], qa[mt], kf);
            }
        }
    }

    int wvr[4], wvm[4][4];
#pragma unroll
    for (int nt = 0; nt < 4; ++nt) wvr[nt] = wvh[nt * 16 + lr];
#pragma unroll
    for (int mt = 0; mt < 4; ++mt)
#pragma unroll
        for (int reg = 0; reg < 4; ++reg) wvm[mt][reg] = wvh[mt * 16 + lg4 * 4 + reg];

    const float scale = 0.2886751345948129f;   // 1/sqrt(12)
    float mxv[4][4], sm[4][4];
#pragma unroll
    for (int mt = 0; mt < 4; ++mt)
#pragma unroll
        for (int reg = 0; reg < 4; ++reg) {
            float mx = -3.0e38f;
#pragma unroll
            for (int nt = 0; nt < 4; ++nt) {
                float v = sc[mt][nt][reg] * scale;
                if (wvr[nt] != wvm[mt][reg]) v += NEGV;
                sc[mt][nt][reg] = v;
                mx = fmaxf(mx, v);
            }
            mxv[mt][reg] = mx;
        }
#pragma unroll
    for (int mt = 0; mt < 4; ++mt)
#pragma unroll
        for (int reg = 0; reg < 4; ++reg) {
            float mx = mxv[mt][reg];
            mx = fmaxf(mx, __shfl_xor(mx, 1));
            mx = fmaxf(mx, __shfl_xor(mx, 2));
            mx = fmaxf(mx, __shfl_xor(mx, 4));
            mx = fmaxf(mx, __shfl_xor(mx, 8));
            mxv[mt][reg] = mx;
        }
#pragma unroll
    for (int mt = 0; mt < 4; ++mt)
#pragma unroll
        for (int reg = 0; reg < 4; ++reg) {
            float s = 0.f;
#pragma unroll
            for (int nt = 0; nt < 4; ++nt) {
                float e = __expf(sc[mt][nt][reg] - mxv[mt][reg]);
                sc[mt][nt][reg] = e;
                s += e;
            }
            sm[mt][reg] = s;
        }
#pragma unroll
    for (int mt = 0; mt < 4; ++mt)
#pragma unroll
        for (int reg = 0; reg < 4; ++reg) {
            float s = sm[mt][reg];
            s += __shfl_xor(s, 1);
            s += __shfl_xor(s, 2);
            s += __shfl_xor(s, 4);
            s += __shfl_xor(s, 8);
            sm[mt][reg] = 1.0f / s;
        }

    // normalize P in-place + write att (f32, fire-and-forget — no readback, no drain)
    float* ab = att_out + ((size_t)((b << 3) + h)) * 2401;
#pragma unroll
    for (int mt = 0; mt < 4; ++mt)
#pragma unroll
        for (int reg = 0; reg < 4; ++reg) {
            int m = mt * 16 + lg4 * 4 + reg;
            float inv = sm[mt][reg];
#pragma unroll
            for (int nt = 0; nt < 4; ++nt) {
                int r = nt * 16 + lr;
                float p = sc[mt][nt][reg] * inv;
                sc[mt][nt][reg] = p;
                if (m < 49 && r < 49) ab[m * 49 + r] = p;
            }
        }

    __syncthreads();   // all waves done reading kq -> region A reusable as pbuf

    // ---- stage P (bf16) into per-head pbuf [49][52] and run PV from LDS ----
    unsigned short* pb = smem + PB_OFF + h * 2548;
#pragma unroll
    for (int mt = 0; mt < 4; ++mt)
#pragma unroll
        for (int reg = 0; reg < 4; ++reg) {
            int m = mt * 16 + lg4 * 4 + reg;
            if (m < 49) {
#pragma unroll
                for (int nt = 0; nt < 4; ++nt) {
                    int r = nt * 16 + lr;
                    if (r < 52) pb[m * 52 + r] = f2bf(sc[mt][nt][reg]);
                }
            }
        }

    // PV: O = P*V via K=16 MFMA x3 (r=0..47) + scalar tail r=48
    f32x4 oc[4];
#pragma unroll
    for (int mt = 0; mt < 4; ++mt) oc[mt] = (f32x4){0.f, 0.f, 0.f, 0.f};
    {
        bf16x4 vf[3];
#pragma unroll
        for (int ks = 0; ks < 3; ++ks)
            vf[ks] = lds_b64(&vt[(h * 12 + lr) * 56 + ks * 16 + lg4 * 4]);
        float v48 = bf2f(vt[(h * 12 + lr) * 56 + 48]);

#pragma unroll
        for (int mt = 0; mt < 4; ++mt) {
            int mrow = mt * 16 + lr; if (mrow > 48) mrow = 48;
            const unsigned short* prow = pb + mrow * 52;
#pragma unroll
            for (int ks = 0; ks < 3; ++ks) {
                bf16x4 pa = lds_b64(prow + ks * 16 + lg4 * 4);
                mfma16(oc[mt], pa, vf[ks]);
            }
#pragma unroll
            for (int reg = 0; reg < 4; ++reg) {
                int m48 = mt * 16 + lg4 * 4 + reg; if (m48 > 48) m48 = 48;
                oc[mt][reg] += bf2f(pb[m48 * 52 + 48]) * v48;
            }
        }
    }
    __syncthreads();   // all PV pbuf reads done -> region A reusable as ostage

    // O -> ostage bf16 (overlays pbuf region)
    unsigned short* ost = smem + OST_OFF;
#pragma unroll
    for (int mt = 0; mt < 4; ++mt)
#pragma unroll
        for (int reg = 0; reg < 4; ++reg) {
            if (lr < 12)
                ost[(mt * 16 + lg4 * 4 + reg) * 104 + h * 12 + lr] = f2bf(oc[mt][reg]);
        }
    __syncthreads();

    // ---- phase 3: output projection (K=32) + inverse-cycle-shift scatter ----
    // cycle_shift(proj, 7, -4): PROPER window partition (window n, patch m ->
    // (Yi,Xi)=((n/8)*7+m/7,(n%8)*7+m%7)) -> roll(-4,-4) -> NAIVE reshape.
    {
        const int mt = w & 3, nh = w >> 2;
        bf16x8 a[3];
#pragma unroll
        for (int ks = 0; ks < 3; ++ks)
            a[ks] = lds_b128(&ost[(mt * 16 + lr) * 104 + ks * 32 + lg4 * 8]);

        size_t orow[4];
        const int wi = n >> 3, wj = n & 7;
#pragma unroll
        for (int reg = 0; reg < 4; ++reg) {
            int m = mt * 16 + lg4 * 4 + reg;
            if (m > 48) m = 48;
            int pi = m / 7, pj = m - pi * 7;
            int Yi = wi * 7 + pi, Xi = wj * 7 + pj;
            int Yo = Yi - 4; if (Yo < 0) Yo += 56;
            int Xo = Xi - 4; if (Xo < 0) Xo += 56;
            orow[reg] = (size_t)(bimg * 3136 + Yo * 56 + Xo) * 96;
        }

#pragma unroll
        for (int j = 0; j < 3; ++j) {
            int nt = nh * 3 + j;
            int col = nt * 16 + lr;
            float bias = b_out[col];
            f32x4 acc = {bias, bias, bias, bias};
#pragma unroll
            for (int ks = 0; ks < 3; ++ks) {
                bf16x8 bf = as_bf16x8(*(const uint4*)(wb2 + (size_t)((nt * 3 + ks) * 64 + l) * 8));
                acc = __builtin_amdgcn_mfma_f32_16x16x32_bf16(a[ks], bf, acc, 0, 0, 0);
            }
#pragma unroll
            for (int reg = 0; reg < 4; ++reg) {
                int m = mt * 16 + lg4 * 4 + reg;
                if (m < 49)
                    out[orow[reg] + col] = acc[reg];
            }
        }
    }
}

extern "C" void kernel_launch(void* const* d_in, const int* in_sizes, int n_in,
                              void* d_out, int out_size, void* d_ws, size_t ws_size,
                              hipStream_t stream) {
    const float* window = (const float*)d_in[0];
    const float* W_kqv  = (const float*)d_in[1];
    const float* b_kqv  = (const float*)d_in[2];
    const float* W_out  = (const float*)d_in[3];
    const float* b_out  = (const float*)d_in[4];

    float* out = (float*)d_out;
    float* att = out + OUT_ELEMS;

    unsigned short* wb = (unsigned short*)d_ws;

    prep_pack<<<144, 256, 0, stream>>>(W_kqv, W_out, wb);
    kfused<<<4096, 512, 0, stream>>>(window, b_kqv, wb, wb + WB2_USH, b_out, att, out);
}